// Round 12
// baseline (112.494 us; speedup 1.0000x reference)
//
#include <hip/hip_runtime.h>
#include <hip/hip_bf16.h>

#define FRADIUS 1.3f
#define FSTEP (2.0f * 1.3f / 128.0f)

typedef __attribute__((ext_vector_type(8))) short short8;
typedef __attribute__((ext_vector_type(16))) float f32x16;

#define MFMA32(a, b, c) __builtin_amdgcn_mfma_f32_32x32x16_bf16((a), (b), (c), 0, 0, 0)

// pack two f32 -> bf16x2 in a dword (RNE); low 16 bits = a
__device__ __forceinline__ unsigned pk2(float a, float b) {
    __hip_bfloat162 hh = __float22bfloat162_rn(make_float2(a, b));
    union { __hip_bfloat162 h; unsigned u; } cv;
    cv.h = hh;
    return cv.u;
}

__device__ __forceinline__ void ray_aabb(float ox, float oy, float oz,
                                         float dx, float dy, float dz,
                                         float& tnear, float& tmax) {
    float sdx = (fabsf(dx) < 1e-9f) ? 1e-9f : dx;
    float sdy = (fabsf(dy) < 1e-9f) ? 1e-9f : dy;
    float sdz = (fabsf(dz) < 1e-9f) ? 1e-9f : dz;
    float t1x = (-FRADIUS - ox) / sdx, t2x = (FRADIUS - ox) / sdx;
    float t1y = (-FRADIUS - oy) / sdy, t2y = (FRADIUS - oy) / sdy;
    float t1z = (-FRADIUS - oz) / sdz, t2z = (FRADIUS - oz) / sdz;
    float tmin = fmaxf(fmaxf(fminf(t1x, t2x), fminf(t1y, t2y)), fminf(t1z, t2z));
    tmax = fminf(fminf(fmaxf(t1x, t2x), fmaxf(t1y, t2y)), fmaxf(t1z, t2z));
    tnear = fmaxf(tmin, 0.0f);
}

// ---------------- weight prep: 32x32x16 A-frags (lane l: A[m=l&31][k=(l>>5)*8+j]) ----------------
// fid map: s0(32->128): 0..7 = nt*2+kt | s1(128->128): 8..39 = 8+nt*8+kt | s2(128->16pad32): 40..47 = 40+kt
//          c0(32->64): 48..51 = 48+nt*2+kt | c1(64->64): 52..59 = 52+nt*4+kt | c2(64->3pad32): 60..63 = 60+kt
__global__ void prep_weights_kernel(const float* __restrict__ s_w0, const float* __restrict__ s_w1,
                                    const float* __restrict__ s_w2, const float* __restrict__ c_w0,
                                    const float* __restrict__ c_w1, const float* __restrict__ c_w2,
                                    uint4* __restrict__ ws) {
    int fid = blockIdx.x;   // 64 frags
    int l = threadIdx.x;    // 64 lanes
    int h = l >> 5, m = l & 31;
    int layer, nt = 0, kt = 0;
    if (fid < 8)       { layer = 0; nt = fid >> 1; kt = fid & 1; }
    else if (fid < 40) { layer = 1; int f = fid - 8;  nt = f >> 3; kt = f & 7; }
    else if (fid < 48) { layer = 2; kt = fid - 40; }
    else if (fid < 52) { layer = 3; int f = fid - 48; nt = f >> 1; kt = f & 1; }
    else if (fid < 60) { layer = 4; int f = fid - 52; nt = f >> 2; kt = f & 3; }
    else               { layer = 5; kt = fid - 60; }
    int n = nt * 32 + m;
    float v[8];
#pragma unroll
    for (int j = 0; j < 8; ++j) {
        int k = kt * 16 + h * 8 + j;
        float x;
        if (layer == 0)      x = s_w0[k * 128 + n];
        else if (layer == 1) x = s_w1[k * 128 + n];
        else if (layer == 2) x = (n < 16) ? s_w2[k * 16 + n] : 0.0f;
        else if (layer == 3) x = (k < 16) ? c_w0[k * 64 + n]
                                 : ((k == 16) ? 0.0f : c_w0[(k - 1) * 64 + n]);  // zero row: sigma unused
        else if (layer == 4) x = c_w1[k * 64 + n];
        else                 x = (n < 3) ? c_w2[k * 3 + n] : 0.0f;
        v[j] = x;
    }
    uint4 u;
    u.x = pk2(v[0], v[1]); u.y = pk2(v[2], v[3]);
    u.z = pk2(v[4], v[5]); u.w = pk2(v[6], v[7]);
    ws[fid * 64 + l] = u;
}

// ---------------- gather one sample point (B-frag layout store) ----------------
__device__ __forceinline__ void gather_one(
    int idx, const float* __restrict__ rays_o, const float* __restrict__ rays_d,
    const float* __restrict__ G1, const float* __restrict__ Fg,
    uint4* __restrict__ fvout) {
    const int ray = idx >> 7;
    const int s = idx & 127;

    const float ox = rays_o[ray * 3 + 0], oy = rays_o[ray * 3 + 1], oz = rays_o[ray * 3 + 2];
    const float dx = rays_d[ray * 3 + 0], dy = rays_d[ray * 3 + 1], dz = rays_d[ray * 3 + 2];

    float tnear, tmax;
    ray_aabb(ox, oy, oz, dx, dy, dz, tnear, tmax);
    float t = tnear + (float)s * FSTEP;
    bool maskb = (t < tmax) && (tmax > tnear);

    uint4* op = fvout + (size_t)(idx >> 5) * 128 + (idx & 31);
    if (!maskb) {
        uint4 z = {0u, 0u, 0u, 0u};
#pragma unroll
        for (int q = 0; q < 4; ++q) op[q * 32] = z;
        return;
    }

    float px = ox + dx * t, py = oy + dy * t, pz = oz + dz * t;
    const float invR = 1.0f / FRADIUS;
    float cx = px * invR, cy = py * invR, cz = pz * invR;

    // G1 trilinear (256^3 x 3)
    float fx = fminf(fmaxf((cx + 1.0f) * 0.5f * 255.0f, 0.0f), 255.0f);
    float fy = fminf(fmaxf((cy + 1.0f) * 0.5f * 255.0f, 0.0f), 255.0f);
    float fz = fminf(fmaxf((cz + 1.0f) * 0.5f * 255.0f, 0.0f), 255.0f);
    float x0f = floorf(fx), y0f = floorf(fy), z0f = floorf(fz);
    float wx = fx - x0f, wy = fy - y0f, wz = fz - z0f;
    int x0 = (int)x0f, y0 = (int)y0f, z0 = (int)z0f;
    int x1 = min(x0 + 1, 255), y1 = min(y0 + 1, 255), z1 = min(z0 + 1, 255);
    float g1x = 0.f, g1y = 0.f, g1z = 0.f;
    {
        float wz0 = 1.f - wz, wy0 = 1.f - wy, wx0 = 1.f - wx;
#pragma unroll
        for (int cc = 0; cc < 8; ++cc) {
            int zz = (cc & 4) ? z1 : z0;
            int yy = (cc & 2) ? y1 : y0;
            int xx = (cc & 1) ? x1 : x0;
            float wgt = ((cc & 4) ? wz : wz0) * ((cc & 2) ? wy : wy0) * ((cc & 1) ? wx : wx0);
            int gidx = (((zz << 8) | yy) << 8 | xx) * 3;
            g1x = fmaf(wgt, G1[gidx + 0], g1x);
            g1y = fmaf(wgt, G1[gidx + 1], g1y);
            g1z = fmaf(wgt, G1[gidx + 2], g1z);
        }
    }

    // Fg trilinear (64^3 x 32)
    float4 fvv[8];
#pragma unroll
    for (int q = 0; q < 8; ++q) fvv[q] = make_float4(0.f, 0.f, 0.f, 0.f);
    {
        float gfx = fminf(fmaxf((g1x + 1.0f) * 0.5f * 63.0f, 0.0f), 63.0f);
        float gfy = fminf(fmaxf((g1y + 1.0f) * 0.5f * 63.0f, 0.0f), 63.0f);
        float gfz = fminf(fmaxf((g1z + 1.0f) * 0.5f * 63.0f, 0.0f), 63.0f);
        float gx0f = floorf(gfx), gy0f = floorf(gfy), gz0f = floorf(gfz);
        float gwx = gfx - gx0f, gwy = gfy - gy0f, gwz = gfz - gz0f;
        int gx0 = (int)gx0f, gy0 = (int)gy0f, gz0 = (int)gz0f;
        int gx1 = min(gx0 + 1, 63), gy1 = min(gy0 + 1, 63), gz1 = min(gz0 + 1, 63);
        float wz0 = 1.f - gwz, wy0 = 1.f - gwy, wx0 = 1.f - gwx;
#pragma unroll
        for (int cc = 0; cc < 8; ++cc) {
            int zz = (cc & 4) ? gz1 : gz0;
            int yy = (cc & 2) ? gy1 : gy0;
            int xx = (cc & 1) ? gx1 : gx0;
            float wgt = ((cc & 4) ? gwz : wz0) * ((cc & 2) ? gwy : wy0) * ((cc & 1) ? gwx : wx0);
            const float4* p = (const float4*)(Fg + (((((zz << 6) | yy) << 6) | xx) << 5));
#pragma unroll
            for (int q = 0; q < 8; ++q) {
                float4 v = p[q];
                fvv[q].x = fmaf(wgt, v.x, fvv[q].x);
                fvv[q].y = fmaf(wgt, v.y, fvv[q].y);
                fvv[q].z = fmaf(wgt, v.z, fvv[q].z);
                fvv[q].w = fmaf(wgt, v.w, fvv[q].w);
            }
        }
    }

#pragma unroll
    for (int q = 0; q < 4; ++q) {
        uint4 u;
        u.x = pk2(fvv[2 * q].x, fvv[2 * q].y);
        u.y = pk2(fvv[2 * q].z, fvv[2 * q].w);
        u.z = pk2(fvv[2 * q + 1].x, fvv[2 * q + 1].y);
        u.w = pk2(fvv[2 * q + 1].z, fvv[2 * q + 1].w);
        op[q * 32] = u;
    }
}

// ---------------- kernel A: gather, 2 samples per thread (latency hiding via ILP) ----------------
__global__ __launch_bounds__(256, 4) void sample_kernel2(
    const float* __restrict__ rays_o, const float* __restrict__ rays_d,
    const float* __restrict__ G1, const float* __restrict__ Fg,
    uint4* __restrict__ fvout) {
    const int base = blockIdx.x * 512 + threadIdx.x;
    gather_one(base, rays_o, rays_d, G1, Fg, fvout);
    gather_one(base + 256, rays_o, rays_d, G1, Fg, fvout);
}

// Build next-layer B-frag from packed activations PK via v_permlane32_swap_b32.
// Equivalent to the r5-validated BUILD_B (xor-32 exchange), but on the VALU pipe:
// swap(x2=PK[2], x0=PK[0]) -> x2'=[PK2_lo,PK0_lo], x0'=[PK2_hi,PK0_hi]
//   u[0] = lo-bcast(PK0) = h ? x2' : PK[0] ;  u[2] = hi-bcast(PK2) = h ? PK[2] : x0'
#define BUILD_B(B, PK, BASE) do {                                          \
    unsigned x2_ = (PK)[(BASE) + 2], x0_ = (PK)[(BASE) + 0];               \
    unsigned x3_ = (PK)[(BASE) + 3], x1_ = (PK)[(BASE) + 1];               \
    asm("v_permlane32_swap_b32 %0, %1" : "+v"(x2_), "+v"(x0_));            \
    asm("v_permlane32_swap_b32 %0, %1" : "+v"(x3_), "+v"(x1_));            \
    union { unsigned u[4]; short8 v; } bb;                                 \
    bb.u[0] = h ? x2_ : (PK)[(BASE) + 0];                                  \
    bb.u[1] = h ? x3_ : (PK)[(BASE) + 1];                                  \
    bb.u[2] = h ? (PK)[(BASE) + 2] : x0_;                                  \
    bb.u[3] = h ? (PK)[(BASE) + 3] : x1_;                                  \
    (B) = bb.v; } while (0)

// ---------------- kernel B: 32x32x16 MLP, 1 tile (32 samples) per wave ----------------
// block = 512 thd = 8 waves = 8 chunks = 2 rays. Pipe split: s0+s1 weights in LDS,
// s2/c0/c1/c2 weights from global (L1/L2-hot). Zero-init folded into first MFMA.
// fvin + ray loads hoisted above the staging barrier.
__global__ __launch_bounds__(512, 4) void mlp_kernel9(
    const float* __restrict__ rays_o, const float* __restrict__ rays_d,
    const uint4* __restrict__ wsg, const short8* __restrict__ fvin,
    float* __restrict__ out) {

    __shared__ uint4 wlds[40 * 64];    // 40 KiB: frags 0..39 (s0 + s1)
    __shared__ float4 comp[2][128];

    const int tid = threadIdx.x;
    const int w = tid >> 6;           // 0..7
    const int lane = tid & 63;
    const int h = lane >> 5;
    const int c = lane & 31;
    const int wr = w >> 2;            // local ray 0/1
    const int chunk = w & 3;          // 32-sample chunk within ray
    const int ray = blockIdx.x * 2 + wr;
    const int cbase = chunk * 32;

    // ---- hoisted global loads (overlap the staging barrier) ----
    short8 xb[2];
    {
        const int g = ray * 4 + chunk;
#pragma unroll
        for (int kt = 0; kt < 2; ++kt)
            xb[kt] = fvin[(size_t)g * 128 + (kt * 2 + h) * 32 + c];
    }
    const float ox = rays_o[ray * 3 + 0], oy = rays_o[ray * 3 + 1], oz = rays_o[ray * 3 + 2];
    const float dx = rays_d[ray * 3 + 0], dy = rays_d[ray * 3 + 1], dz = rays_d[ray * 3 + 2];

    // ---- stage s0+s1 weight frags into LDS (coalesced, one-time) ----
#pragma unroll
    for (int i = 0; i < 5; ++i) wlds[tid + i * 512] = wsg[tid + i * 512];
    __syncthreads();

    float tnear, tmax;
    ray_aabb(ox, oy, oz, dx, dy, dz, tnear, tmax);
    const bool hit = (tmax > tnear);
    const bool dead = !hit || (tnear + (float)cbase * FSTEP >= tmax);  // masked = suffix

    if (dead) {
        if (lane < 32) comp[wr][cbase + lane] = make_float4(0.f, 0.f, 0.f, 0.f);
    } else {
        const f32x16 z16 = {0.f};

        // ---- s0: 32 -> 128 ; outputs emitted directly as next-layer B-frags b0f[8] ----
        short8 b0f[8];
#pragma unroll
        for (int nt = 0; nt < 4; ++nt) {
            f32x16 a = MFMA32(*(const short8*)&wlds[(nt * 2 + 0) * 64 + lane], xb[0], z16);
            a = MFMA32(*(const short8*)&wlds[(nt * 2 + 1) * 64 + lane], xb[1], a);
            unsigned pkt[8];
#pragma unroll
            for (int p = 0; p < 8; ++p)
                pkt[p] = pk2(fmaxf(a[2 * p], 0.f), fmaxf(a[2 * p + 1], 0.f));
            BUILD_B(b0f[2 * nt + 0], pkt, 0);
            BUILD_B(b0f[2 * nt + 1], pkt, 4);
        }

        // ---- s1: 128 -> 128 (LDS weights; inner loop pure {ds_read, MFMA}) ----
        short8 b1f[8];
#pragma unroll
        for (int nt = 0; nt < 4; ++nt) {
            f32x16 a = MFMA32(*(const short8*)&wlds[(8 + nt * 8 + 0) * 64 + lane], b0f[0], z16);
#pragma unroll
            for (int kt = 1; kt < 8; ++kt) {
                short8 wv = *(const short8*)&wlds[(8 + nt * 8 + kt) * 64 + lane];
                a = MFMA32(wv, b0f[kt], a);
            }
            unsigned pkt[8];
#pragma unroll
            for (int p = 0; p < 8; ++p)
                pkt[p] = pk2(fmaxf(a[2 * p], 0.f), fmaxf(a[2 * p + 1], 0.f));
            BUILD_B(b1f[2 * nt + 0], pkt, 0);
            BUILD_B(b1f[2 * nt + 1], pkt, 4);
        }

        // ---- s2: 128 -> 16 (raw); weights from global (L1/L2-hot) ----
        short8 Bsig;
        float alphaR;
        {
            f32x16 S = MFMA32(*(const short8*)&wsg[(40 + 0) * 64 + lane], b1f[0], z16);
#pragma unroll
            for (int kt = 1; kt < 8; ++kt) {
                short8 wv = *(const short8*)&wsg[(40 + kt) * 64 + lane];
                S = MFMA32(wv, b1f[kt], S);
            }
            unsigned s2p[4];
#pragma unroll
            for (int p = 0; p < 4; ++p) s2p[p] = pk2(S[2 * p], S[2 * p + 1]);
            BUILD_B(Bsig, s2p, 0);
            float tp = tnear + (float)(cbase + c) * FSTEP;
            float sg = fmaxf(S[0], 0.f);
            alphaR = (tp < tmax) ? 1.0f - __expf(-sg * FSTEP) : 0.0f;
        }

        // ---- SH deg-4 enc (computed late to shrink live range) ----
        short8 Benc;
        {
            float inv = rsqrtf(dx * dx + dy * dy + dz * dz);
            float nx = dx * inv, ny = dy * inv, nz = dz * inv;
            float nx2 = nx * nx, ny2 = ny * ny, nz2 = nz * nz;
            float nxy = nx * ny, nyz = ny * nz, nxz = nx * nz;
            float e0 = 0.28209479177387814f;
            float e1 = -0.48860251190291987f * ny;
            float e2 = 0.48860251190291987f * nz;
            float e3 = -0.48860251190291987f * nx;
            float e4 = 1.0925484305920792f * nxy;
            float e5 = -1.0925484305920792f * nyz;
            float e6 = 0.94617469575756f * nz2 - 0.31539156525252f;
            float e7 = -1.0925484305920792f * nxz;
            float e8 = 0.5462742152960396f * (nx2 - ny2);
            float e9 = 0.5900435899266435f * ny * (-3.0f * nx2 + ny2);
            float e10 = 2.890611442640554f * nxy * nz;
            float e11 = 0.4570457994644657f * ny * (1.0f - 5.0f * nz2);
            float e12 = 0.3731763325901154f * nz * (5.0f * nz2 - 3.0f);
            float e13 = 0.4570457994644657f * nx * (1.0f - 5.0f * nz2);
            float e14 = 1.445305721320277f * nz * (nx2 - ny2);
            float e15 = 0.5900435899266435f * nx * (-nx2 + 3.0f * ny2);
            union { unsigned u[4]; short8 v; } bb;
            bb.u[0] = h ? pk2(e8, e9)   : pk2(e0, e1);
            bb.u[1] = h ? pk2(e10, e11) : pk2(e2, e3);
            bb.u[2] = h ? pk2(e12, e13) : pk2(e4, e5);
            bb.u[3] = h ? pk2(e14, e15) : pk2(e6, e7);
            Benc = bb.v;
        }

        // ---- c0: [enc|sig] 32 -> 64 ; weights from global ----
        short8 c0f[4];
#pragma unroll
        for (int nt = 0; nt < 2; ++nt) {
            f32x16 a = MFMA32(*(const short8*)&wsg[(48 + nt * 2 + 0) * 64 + lane], Benc, z16);
            a = MFMA32(*(const short8*)&wsg[(48 + nt * 2 + 1) * 64 + lane], Bsig, a);
            unsigned pkt[8];
#pragma unroll
            for (int p = 0; p < 8; ++p)
                pkt[p] = pk2(fmaxf(a[2 * p], 0.f), fmaxf(a[2 * p + 1], 0.f));
            BUILD_B(c0f[2 * nt + 0], pkt, 0);
            BUILD_B(c0f[2 * nt + 1], pkt, 4);
        }

        // ---- c1: 64 -> 64 ; weights from global ----
        short8 c1f[4];
#pragma unroll
        for (int nt = 0; nt < 2; ++nt) {
            f32x16 a = MFMA32(*(const short8*)&wsg[(52 + nt * 4 + 0) * 64 + lane], c0f[0], z16);
#pragma unroll
            for (int kt = 1; kt < 4; ++kt) {
                short8 wv = *(const short8*)&wsg[(52 + nt * 4 + kt) * 64 + lane];
                a = MFMA32(wv, c0f[kt], a);
            }
            unsigned pkt[8];
#pragma unroll
            for (int p = 0; p < 8; ++p)
                pkt[p] = pk2(fmaxf(a[2 * p], 0.f), fmaxf(a[2 * p + 1], 0.f));
            BUILD_B(c1f[2 * nt + 0], pkt, 0);
            BUILD_B(c1f[2 * nt + 1], pkt, 4);
        }

        // ---- c2: 64 -> 3 ; weights from global ----
        {
            f32x16 F = MFMA32(*(const short8*)&wsg[(60 + 0) * 64 + lane], c1f[0], z16);
#pragma unroll
            for (int kt = 1; kt < 4; ++kt) {
                short8 wv = *(const short8*)&wsg[(60 + kt) * 64 + lane];
                F = MFMA32(wv, c1f[kt], F);
            }
            if (h == 0) {  // rows n=0,1,2 live on half 0, regs 0..2
                float4 cv;
                cv.x = alphaR;
                cv.y = 1.0f / (1.0f + __expf(-F[0]));
                cv.z = 1.0f / (1.0f + __expf(-F[1]));
                cv.w = 1.0f / (1.0f + __expf(-F[2]));
                comp[wr][cbase + c] = cv;
            }
        }
    }

    __syncthreads();

    // ---- composite: waves 0,1 each scan one ray ----
    if (tid < 128) {
        const int cr = tid >> 6;   // local ray 0/1
        const int ln = tid & 63;
        float4 vl = comp[cr][ln];
        float4 vh = comp[cr][ln + 64];
        float a_lo = vl.x, a_hi = vh.x;
        float m_lo = 1.0f - a_lo + 1e-10f;
        float m_hi = 1.0f - a_hi + 1e-10f;

        float p = m_lo;
#pragma unroll
        for (int off = 1; off < 64; off <<= 1) {
            float q = __shfl_up(p, off, 64);
            if (ln >= off) p *= q;
        }
        float ph = m_hi;
#pragma unroll
        for (int off = 1; off < 64; off <<= 1) {
            float q = __shfl_up(ph, off, 64);
            if (ln >= off) ph *= q;
        }
        float total_lo = __shfl(p, 63, 64);
        float e_lo = __shfl_up(p, 1, 64);
        if (ln == 0) e_lo = 1.0f;
        float e_hi = __shfl_up(ph, 1, 64);
        if (ln == 0) e_hi = 1.0f;
        e_hi *= total_lo;

        float w_lo = a_lo * e_lo;
        float w_hi = a_hi * e_hi;

        float sr = w_lo * vl.y + w_hi * vh.y;
        float sg = w_lo * vl.z + w_hi * vh.z;
        float sb = w_lo * vl.w + w_hi * vh.w;
        float sw = w_lo + w_hi;
#pragma unroll
        for (int off = 32; off >= 1; off >>= 1) {
            sr += __shfl_xor(sr, off, 64);
            sg += __shfl_xor(sg, off, 64);
            sb += __shfl_xor(sb, off, 64);
            sw += __shfl_xor(sw, off, 64);
        }
        if (ln == 0) {
            int rg = blockIdx.x * 2 + cr;
            float bg = 1.0f - sw;
            out[rg * 3 + 0] = sr + bg;
            out[rg * 3 + 1] = sg + bg;
            out[rg * 3 + 2] = sb + bg;
        }
    }
}

extern "C" void kernel_launch(void* const* d_in, const int* in_sizes, int n_in,
                              void* d_out, int out_size, void* d_ws, size_t ws_size,
                              hipStream_t stream) {
    const float* rays_o = (const float*)d_in[0];
    const float* rays_d = (const float*)d_in[1];
    const float* G1 = (const float*)d_in[2];
    const float* Fg = (const float*)d_in[3];
    const float* s_w0 = (const float*)d_in[4];
    const float* s_w1 = (const float*)d_in[5];
    const float* s_w2 = (const float*)d_in[6];
    const float* c_w0 = (const float*)d_in[7];
    const float* c_w1 = (const float*)d_in[8];
    const float* c_w2 = (const float*)d_in[9];
    float* out = (float*)d_out;

    const int B = in_sizes[0] / 3;  // 8192 rays
    const int npts = B * 128;

    const size_t FV_OFF = 65536;
    const size_t need = FV_OFF + (size_t)npts * 64;
    if (ws_size < need) return;  // observed ws_size ~805 MB >> 84 MB needed

    uint4* fv = (uint4*)((char*)d_ws + FV_OFF);

    prep_weights_kernel<<<dim3(64), dim3(64), 0, stream>>>(s_w0, s_w1, s_w2, c_w0, c_w1, c_w2,
                                                           (uint4*)d_ws);
    sample_kernel2<<<dim3(npts / 512), dim3(256), 0, stream>>>(rays_o, rays_d, G1, Fg, fv);
    mlp_kernel9<<<dim3(B / 2), dim3(512), 0, stream>>>(rays_o, rays_d, (const uint4*)d_ws,
                                                       (const short8*)fv, out);
}

// Round 13
// 90.006 us; speedup vs baseline: 1.2498x; 1.2498x over previous
//
#include <hip/hip_runtime.h>
#include <hip/hip_bf16.h>

#define FRADIUS 1.3f
#define FSTEP (2.0f * 1.3f / 128.0f)

typedef __attribute__((ext_vector_type(8))) int int8v;
typedef __attribute__((ext_vector_type(16))) float f32x16;

// MX-scaled fp8 MFMA, 32x32x64, A=B=e4m3. Scales: A byte 121 (2^-6, weights stored x64),
// B byte 127 (2^0, activations carried x2^8). D = 2^6 * 2^8 * 2^-6 * (W.X) = 2^8 * true.
#define MFMAS(a, b, c) \
    __builtin_amdgcn_mfma_scale_f32_32x32x64_f8f6f4((a), (b), (c), 0, 0, 0, 121, 0, 127)

// pack 4 f32 -> 4 fp8 (e4m3) bytes in a dword
__device__ __forceinline__ unsigned pkf8(float a, float b, float c2, float d) {
    int t = __builtin_amdgcn_cvt_pk_fp8_f32(a, b, 0, false);
    t = __builtin_amdgcn_cvt_pk_fp8_f32(c2, d, t, true);
    return (unsigned)t;
}

__device__ __forceinline__ void ray_aabb(float ox, float oy, float oz,
                                         float dx, float dy, float dz,
                                         float& tnear, float& tmax) {
    float sdx = (fabsf(dx) < 1e-9f) ? 1e-9f : dx;
    float sdy = (fabsf(dy) < 1e-9f) ? 1e-9f : dy;
    float sdz = (fabsf(dz) < 1e-9f) ? 1e-9f : dz;
    float t1x = (-FRADIUS - ox) / sdx, t2x = (FRADIUS - ox) / sdx;
    float t1y = (-FRADIUS - oy) / sdy, t2y = (FRADIUS - oy) / sdy;
    float t1z = (-FRADIUS - oz) / sdz, t2z = (FRADIUS - oz) / sdz;
    float tmin = fmaxf(fmaxf(fminf(t1x, t2x), fminf(t1y, t2y)), fminf(t1z, t2z));
    tmax = fminf(fminf(fmaxf(t1x, t2x), fmaxf(t1y, t2y)), fmaxf(t1z, t2z));
    tnear = fmaxf(tmin, 0.0f);
}

// ---------------- weight prep: fp8 32x32x64 A-frags (x64, e4m3) ----------------
// A layout: lane l: m = l&31, k = (l>>5)*32 + j, byte j of 8 dwords (little-endian).
// Storage: uint4 ws[fid*128 + half*64 + lane], half0 = dwords 0-3, half1 = dwords 4-7.
// fid: s0: 0..3 (nt) | s1: 4+nt*2+kt | s2: 12+kt | c0: 14+nt | c1: 16+nt | c2: 18
__global__ void prep_weights_kernel(const float* __restrict__ s_w0, const float* __restrict__ s_w1,
                                    const float* __restrict__ s_w2, const float* __restrict__ c_w0,
                                    const float* __restrict__ c_w1, const float* __restrict__ c_w2,
                                    uint4* __restrict__ ws) {
    const int fid = blockIdx.x;   // 0..18
    const int l = threadIdx.x;    // 64 lanes
    const int hA = l >> 5, m = l & 31;
    float v[32];
#pragma unroll
    for (int j = 0; j < 32; ++j) {
        const int kl = hA * 32 + j;  // k within the frag's 64
        float x = 0.0f;
        if (fid < 4) {                       // s0: 32->128, real k<32
            if (kl < 32) x = s_w0[kl * 128 + fid * 32 + m];
        } else if (fid < 12) {               // s1: 128->128
            int t = fid - 4, nt = t >> 1, kt = t & 1;
            x = s_w1[(kt * 64 + kl) * 128 + nt * 32 + m];
        } else if (fid < 14) {               // s2: 128->16 (pad n to 32)
            int kt = fid - 12;
            if (m < 16) x = s_w2[(kt * 64 + kl) * 16 + m];
        } else if (fid < 16) {               // c0: 32(31)->64, real k<32; zero row at k=16
            int nt = fid - 14;
            if (kl < 16) x = c_w0[kl * 64 + nt * 32 + m];
            else if (kl > 16 && kl < 32) x = c_w0[(kl - 1) * 64 + nt * 32 + m];
        } else if (fid < 18) {               // c1: 64->64
            int nt = fid - 16;
            x = c_w1[kl * 64 + nt * 32 + m];
        } else {                             // c2: 64->3 (pad n to 32)
            if (m < 3) x = c_w2[kl * 3 + m];
        }
        v[j] = 64.0f * x;
    }
    uint4 lo, hi;
    lo.x = pkf8(v[0], v[1], v[2], v[3]);    lo.y = pkf8(v[4], v[5], v[6], v[7]);
    lo.z = pkf8(v[8], v[9], v[10], v[11]);  lo.w = pkf8(v[12], v[13], v[14], v[15]);
    hi.x = pkf8(v[16], v[17], v[18], v[19]); hi.y = pkf8(v[20], v[21], v[22], v[23]);
    hi.z = pkf8(v[24], v[25], v[26], v[27]); hi.w = pkf8(v[28], v[29], v[30], v[31]);
    ws[fid * 128 + l] = lo;
    ws[fid * 128 + 64 + l] = hi;
}

// ---------------- kernel A: gather (1 thread = 1 sample); fp8 output x2^8 ----------------
// fv frag: sample idx stores 8 dwords (32 fp8 bytes, feature j = byte j) at fvout[idx*2 +0/1]
__global__ __launch_bounds__(256) void sample_kernel(
    const float* __restrict__ rays_o, const float* __restrict__ rays_d,
    const float* __restrict__ G1, const float* __restrict__ Fg,
    uint4* __restrict__ fvout) {
    const int idx = blockIdx.x * 256 + threadIdx.x;
    const int ray = idx >> 7;
    const int s = idx & 127;

    const float ox = rays_o[ray * 3 + 0], oy = rays_o[ray * 3 + 1], oz = rays_o[ray * 3 + 2];
    const float dx = rays_d[ray * 3 + 0], dy = rays_d[ray * 3 + 1], dz = rays_d[ray * 3 + 2];

    float tnear, tmax;
    ray_aabb(ox, oy, oz, dx, dy, dz, tnear, tmax);
    float t = tnear + (float)s * FSTEP;
    bool maskb = (t < tmax) && (tmax > tnear);

    uint4* op = fvout + (size_t)idx * 2;
    if (!maskb) {
        uint4 z = {0u, 0u, 0u, 0u};
        op[0] = z; op[1] = z;
        return;
    }

    float px = ox + dx * t, py = oy + dy * t, pz = oz + dz * t;
    const float invR = 1.0f / FRADIUS;
    float cx = px * invR, cy = py * invR, cz = pz * invR;

    // G1 trilinear (256^3 x 3)
    float fx = fminf(fmaxf((cx + 1.0f) * 0.5f * 255.0f, 0.0f), 255.0f);
    float fy = fminf(fmaxf((cy + 1.0f) * 0.5f * 255.0f, 0.0f), 255.0f);
    float fz = fminf(fmaxf((cz + 1.0f) * 0.5f * 255.0f, 0.0f), 255.0f);
    float x0f = floorf(fx), y0f = floorf(fy), z0f = floorf(fz);
    float wx = fx - x0f, wy = fy - y0f, wz = fz - z0f;
    int x0 = (int)x0f, y0 = (int)y0f, z0 = (int)z0f;
    int x1 = min(x0 + 1, 255), y1 = min(y0 + 1, 255), z1 = min(z0 + 1, 255);
    float g1x = 0.f, g1y = 0.f, g1z = 0.f;
    {
        float wz0 = 1.f - wz, wy0 = 1.f - wy, wx0 = 1.f - wx;
#pragma unroll
        for (int cc = 0; cc < 8; ++cc) {
            int zz = (cc & 4) ? z1 : z0;
            int yy = (cc & 2) ? y1 : y0;
            int xx = (cc & 1) ? x1 : x0;
            float wgt = ((cc & 4) ? wz : wz0) * ((cc & 2) ? wy : wy0) * ((cc & 1) ? wx : wx0);
            int gidx = (((zz << 8) | yy) << 8 | xx) * 3;
            g1x = fmaf(wgt, G1[gidx + 0], g1x);
            g1y = fmaf(wgt, G1[gidx + 1], g1y);
            g1z = fmaf(wgt, G1[gidx + 2], g1z);
        }
    }

    // Fg trilinear (64^3 x 32); accumulate x2^8 (weights pre-scaled)
    float4 fvv[8];
#pragma unroll
    for (int q = 0; q < 8; ++q) fvv[q] = make_float4(0.f, 0.f, 0.f, 0.f);
    {
        float gfx = fminf(fmaxf((g1x + 1.0f) * 0.5f * 63.0f, 0.0f), 63.0f);
        float gfy = fminf(fmaxf((g1y + 1.0f) * 0.5f * 63.0f, 0.0f), 63.0f);
        float gfz = fminf(fmaxf((g1z + 1.0f) * 0.5f * 63.0f, 0.0f), 63.0f);
        float gx0f = floorf(gfx), gy0f = floorf(gfy), gz0f = floorf(gfz);
        float gwx = gfx - gx0f, gwy = gfy - gy0f, gwz = gfz - gz0f;
        int gx0 = (int)gx0f, gy0 = (int)gy0f, gz0 = (int)gz0f;
        int gx1 = min(gx0 + 1, 63), gy1 = min(gy0 + 1, 63), gz1 = min(gz0 + 1, 63);
        float wz0 = 1.f - gwz, wy0 = 1.f - gwy, wx0 = 1.f - gwx;
#pragma unroll
        for (int cc = 0; cc < 8; ++cc) {
            int zz = (cc & 4) ? gz1 : gz0;
            int yy = (cc & 2) ? gy1 : gy0;
            int xx = (cc & 1) ? gx1 : gx0;
            float wgt = 256.0f * ((cc & 4) ? gwz : wz0) * ((cc & 2) ? gwy : wy0) *
                        ((cc & 1) ? gwx : wx0);
            const float4* p = (const float4*)(Fg + (((((zz << 6) | yy) << 6) | xx) << 5));
#pragma unroll
            for (int q = 0; q < 8; ++q) {
                float4 v = p[q];
                fvv[q].x = fmaf(wgt, v.x, fvv[q].x);
                fvv[q].y = fmaf(wgt, v.y, fvv[q].y);
                fvv[q].z = fmaf(wgt, v.z, fvv[q].z);
                fvv[q].w = fmaf(wgt, v.w, fvv[q].w);
            }
        }
    }

    uint4 lo, hi;
    lo.x = pkf8(fvv[0].x, fvv[0].y, fvv[0].z, fvv[0].w);
    lo.y = pkf8(fvv[1].x, fvv[1].y, fvv[1].z, fvv[1].w);
    lo.z = pkf8(fvv[2].x, fvv[2].y, fvv[2].z, fvv[2].w);
    lo.w = pkf8(fvv[3].x, fvv[3].y, fvv[3].z, fvv[3].w);
    hi.x = pkf8(fvv[4].x, fvv[4].y, fvv[4].z, fvv[4].w);
    hi.y = pkf8(fvv[5].x, fvv[5].y, fvv[5].z, fvv[5].w);
    hi.z = pkf8(fvv[6].x, fvv[6].y, fvv[6].z, fvv[6].w);
    hi.w = pkf8(fvv[7].x, fvv[7].y, fvv[7].z, fvv[7].w);
    op[0] = lo; op[1] = hi;
}

// relu + pack one tile's 16 f32 regs -> 4 dwords: dst[q] bytes = regs 4q..4q+3
#define PACKR(dst, a) do {                                                              \
    (dst)[0] = pkf8(fmaxf((a)[0], 0.f), fmaxf((a)[1], 0.f), fmaxf((a)[2], 0.f), fmaxf((a)[3], 0.f)); \
    (dst)[1] = pkf8(fmaxf((a)[4], 0.f), fmaxf((a)[5], 0.f), fmaxf((a)[6], 0.f), fmaxf((a)[7], 0.f)); \
    (dst)[2] = pkf8(fmaxf((a)[8], 0.f), fmaxf((a)[9], 0.f), fmaxf((a)[10], 0.f), fmaxf((a)[11], 0.f)); \
    (dst)[3] = pkf8(fmaxf((a)[12], 0.f), fmaxf((a)[13], 0.f), fmaxf((a)[14], 0.f), fmaxf((a)[15], 0.f)); \
} while (0)

// Build one K=64 B-frag from output tiles TA (rows 32T..), TB (rows 32T+32..).
// C/D row map: row = (r&3)+8*(r>>2)+4*h'.  B byte j (dword d=j>>2) needs tile (h? TB:TA),
// within-tile row 4d+b -> source dword q=d>>1 from half h_src=d&1. Partner half via shfl_xor 32.
#define BUILD2(B, TA, TB) do {                                                          \
    union { unsigned u[8]; int8v v; } bb_;                                              \
    _Pragma("unroll")                                                                   \
    for (int q_ = 0; q_ < 4; ++q_) {                                                    \
        unsigned snd_ = h ? (TA)[q_] : (TB)[q_];                                        \
        unsigned rec_ = (unsigned)__shfl_xor((int)snd_, 32, 64);                        \
        unsigned own_ = h ? (TB)[q_] : (TA)[q_];                                        \
        bb_.u[2 * q_]     = h ? rec_ : own_;                                            \
        bb_.u[2 * q_ + 1] = h ? own_ : rec_;                                            \
    }                                                                                   \
    (B) = bb_.v; } while (0)

// ---------------- kernel B: fp8 MX MFMA MLP, 1 tile (32 samples) per wave ----------------
// block = 512 thd = 8 waves = 8 chunks = 2 rays. 19 MFMAs/wave (vs 64 bf16).
// LDS = 38 KB weights + 4 KB comp; VGPR cap 128 (4 waves/EU).
__global__ __launch_bounds__(512, 4) void mlp_fp8_kernel(
    const float* __restrict__ rays_o, const float* __restrict__ rays_d,
    const uint4* __restrict__ wsg, const uint4* __restrict__ fvin,
    float* __restrict__ out) {

    __shared__ uint4 wlds[19 * 128];   // 38 KiB
    __shared__ float4 comp[2][128];

    const int tid = threadIdx.x;
    const int w = tid >> 6;
    const int lane = tid & 63;
    const int h = lane >> 5;
    const int c = lane & 31;
    const int wr = w >> 2;
    const int chunk = w & 3;
    const int ray = blockIdx.x * 2 + wr;
    const int cbase = chunk * 32;

    // stage all fp8 weight frags (2432 uint4)
#pragma unroll
    for (int i = 0; i < 5; ++i) {
        int tt = tid + i * 512;
        if (tt < 19 * 128) wlds[tt] = wsg[tt];
    }
    __syncthreads();

    const float ox = rays_o[ray * 3 + 0], oy = rays_o[ray * 3 + 1], oz = rays_o[ray * 3 + 2];
    const float dx = rays_d[ray * 3 + 0], dy = rays_d[ray * 3 + 1], dz = rays_d[ray * 3 + 2];

    float tnear, tmax;
    ray_aabb(ox, oy, oz, dx, dy, dz, tnear, tmax);
    const bool hit = (tmax > tnear);
    const bool dead = !hit || (tnear + (float)cbase * FSTEP >= tmax);

    if (dead) {
        if (lane < 32) comp[wr][cbase + lane] = make_float4(0.f, 0.f, 0.f, 0.f);
    } else {
        const f32x16 z16 = {0.f};

        // A-frag loader (conflict-free: two contiguous 16B reads)
        auto AF = [&](int f) -> int8v {
            union { uint4 u4[2]; int8v v; } t;
            t.u4[0] = wlds[f * 128 + lane];
            t.u4[1] = wlds[f * 128 + 64 + lane];
            return t.v;
        };

        // ---- fv B-frag: h=0 half holds 32 features, h=1 half = zero pad ----
        int8v xb;
        {
            union { uint4 u4[2]; int8v v; } bb;
            uint4 z = {0u, 0u, 0u, 0u};
            if (h == 0) {
                size_t p = (size_t)(ray * 128 + cbase + c) * 2;
                bb.u4[0] = fvin[p];
                bb.u4[1] = fvin[p + 1];
            } else {
                bb.u4[0] = z; bb.u4[1] = z;
            }
            xb = bb.v;
        }

        // ---- s0: 32 -> 128 (4 MFMA) ----
        unsigned o0[4][4];
#pragma unroll
        for (int nt = 0; nt < 4; ++nt) {
            f32x16 a = MFMAS(AF(nt), xb, z16);
            PACKR(o0[nt], a);
        }
        int8v b0k0, b0k1;
        BUILD2(b0k0, o0[0], o0[1]);
        BUILD2(b0k1, o0[2], o0[3]);

        // ---- s1: 128 -> 128 (8 MFMA) ----
        unsigned o1[4][4];
#pragma unroll
        for (int nt = 0; nt < 4; ++nt) {
            f32x16 a = MFMAS(AF(4 + nt * 2 + 0), b0k0, z16);
            a = MFMAS(AF(4 + nt * 2 + 1), b0k1, a);
            PACKR(o1[nt], a);
        }
        int8v b1k0, b1k1;
        BUILD2(b1k0, o1[0], o1[1]);
        BUILD2(b1k1, o1[2], o1[3]);

        // ---- s2: 128 -> 16 (2 MFMA, raw outputs) ----
        f32x16 S = MFMAS(AF(12), b1k0, z16);
        S = MFMAS(AF(13), b1k1, S);
        unsigned os2[2];
        os2[0] = pkf8(S[0], S[1], S[2], S[3]);      // rows 4h'+0..3 (tile rows 0-3 / 4-7)
        os2[1] = pkf8(S[4], S[5], S[6], S[7]);      // rows 8+4h'+0..3
        float alphaR;
        {
            float tp = tnear + (float)(cbase + c) * FSTEP;
            float sg = fmaxf(S[0], 0.f) * (1.0f / 256.0f);   // row 0 at h'=0 = sigma
            alphaR = (tp < tmax) ? 1.0f - __expf(-sg * FSTEP) : 0.0f;
        }

        // ---- cin B-frag: k0..15 = enc, k16 = 0, k17..31 = sig rows 1..15; h=1 half zero ----
        int8v bc;
        {
            unsigned rec0 = (unsigned)__shfl_xor((int)os2[0], 32, 64);
            unsigned rec1 = (unsigned)__shfl_xor((int)os2[1], 32, 64);
            union { unsigned u[8]; int8v v; } bb;
            if (h == 0) {
                float inv = rsqrtf(dx * dx + dy * dy + dz * dz);
                float nx = dx * inv, ny = dy * inv, nz = dz * inv;
                float nx2 = nx * nx, ny2 = ny * ny, nz2 = nz * nz;
                float nxy = nx * ny, nyz = ny * nz, nxz = nx * nz;
                // enc x2^8 (constants folded)
                float e0 = 256.0f * 0.28209479177387814f;
                float e1 = 256.0f * -0.48860251190291987f * ny;
                float e2 = 256.0f * 0.48860251190291987f * nz;
                float e3 = 256.0f * -0.48860251190291987f * nx;
                float e4 = 256.0f * 1.0925484305920792f * nxy;
                float e5 = 256.0f * -1.0925484305920792f * nyz;
                float e6 = 256.0f * (0.94617469575756f * nz2 - 0.31539156525252f);
                float e7 = 256.0f * -1.0925484305920792f * nxz;
                float e8 = 256.0f * 0.5462742152960396f * (nx2 - ny2);
                float e9 = 256.0f * 0.5900435899266435f * ny * (-3.0f * nx2 + ny2);
                float e10 = 256.0f * 2.890611442640554f * nxy * nz;
                float e11 = 256.0f * 0.4570457994644657f * ny * (1.0f - 5.0f * nz2);
                float e12 = 256.0f * 0.3731763325901154f * nz * (5.0f * nz2 - 3.0f);
                float e13 = 256.0f * 0.4570457994644657f * nx * (1.0f - 5.0f * nz2);
                float e14 = 256.0f * 1.445305721320277f * nz * (nx2 - ny2);
                float e15 = 256.0f * 0.5900435899266435f * nx * (-nx2 + 3.0f * ny2);
                bb.u[0] = pkf8(e0, e1, e2, e3);
                bb.u[1] = pkf8(e4, e5, e6, e7);
                bb.u[2] = pkf8(e8, e9, e10, e11);
                bb.u[3] = pkf8(e12, e13, e14, e15);
                bb.u[4] = os2[0] & 0xFFFFFF00u;  // [0, sig1, sig2, sig3]
                bb.u[5] = rec0;                  // sig rows 4..7 (partner h'=1)
                bb.u[6] = os2[1];                // rows 8..11
                bb.u[7] = rec1;                  // rows 12..15 (partner)
            } else {
#pragma unroll
                for (int q = 0; q < 8; ++q) bb.u[q] = 0u;
            }
            bc = bb.v;
        }

        // ---- c0: 32 -> 64 (2 MFMA) ----
        unsigned oc0[2][4];
#pragma unroll
        for (int nt = 0; nt < 2; ++nt) {
            f32x16 a = MFMAS(AF(14 + nt), bc, z16);
            PACKR(oc0[nt], a);
        }
        int8v bcc;
        BUILD2(bcc, oc0[0], oc0[1]);

        // ---- c1: 64 -> 64 (2 MFMA) ----
        unsigned oc1[2][4];
#pragma unroll
        for (int nt = 0; nt < 2; ++nt) {
            f32x16 a = MFMAS(AF(16 + nt), bcc, z16);
            PACKR(oc1[nt], a);
        }
        int8v bd;
        BUILD2(bd, oc1[0], oc1[1]);

        // ---- c2: 64 -> 3 (1 MFMA) ----
        {
            f32x16 F = MFMAS(AF(18), bd, z16);
            if (h == 0) {  // rows 0..2 on half 0, regs 0..2
                const float s8 = 1.0f / 256.0f;
                float4 cv;
                cv.x = alphaR;
                cv.y = 1.0f / (1.0f + __expf(-F[0] * s8));
                cv.z = 1.0f / (1.0f + __expf(-F[1] * s8));
                cv.w = 1.0f / (1.0f + __expf(-F[2] * s8));
                comp[wr][cbase + c] = cv;
            }
        }
    }

    __syncthreads();

    // ---- composite: waves 0,1 each scan one ray ----
    if (tid < 128) {
        const int cr = tid >> 6;
        const int ln = tid & 63;
        float4 vl = comp[cr][ln];
        float4 vh = comp[cr][ln + 64];
        float a_lo = vl.x, a_hi = vh.x;
        float m_lo = 1.0f - a_lo + 1e-10f;
        float m_hi = 1.0f - a_hi + 1e-10f;

        float p = m_lo;
#pragma unroll
        for (int off = 1; off < 64; off <<= 1) {
            float q = __shfl_up(p, off, 64);
            if (ln >= off) p *= q;
        }
        float ph = m_hi;
#pragma unroll
        for (int off = 1; off < 64; off <<= 1) {
            float q = __shfl_up(ph, off, 64);
            if (ln >= off) ph *= q;
        }
        float total_lo = __shfl(p, 63, 64);
        float e_lo = __shfl_up(p, 1, 64);
        if (ln == 0) e_lo = 1.0f;
        float e_hi = __shfl_up(ph, 1, 64);
        if (ln == 0) e_hi = 1.0f;
        e_hi *= total_lo;

        float w_lo = a_lo * e_lo;
        float w_hi = a_hi * e_hi;

        float sr = w_lo * vl.y + w_hi * vh.y;
        float sg = w_lo * vl.z + w_hi * vh.z;
        float sb = w_lo * vl.w + w_hi * vh.w;
        float sw = w_lo + w_hi;
#pragma unroll
        for (int off = 32; off >= 1; off >>= 1) {
            sr += __shfl_xor(sr, off, 64);
            sg += __shfl_xor(sg, off, 64);
            sb += __shfl_xor(sb, off, 64);
            sw += __shfl_xor(sw, off, 64);
        }
        if (ln == 0) {
            int rg = blockIdx.x * 2 + cr;
            float bg = 1.0f - sw;
            out[rg * 3 + 0] = sr + bg;
            out[rg * 3 + 1] = sg + bg;
            out[rg * 3 + 2] = sb + bg;
        }
    }
}

extern "C" void kernel_launch(void* const* d_in, const int* in_sizes, int n_in,
                              void* d_out, int out_size, void* d_ws, size_t ws_size,
                              hipStream_t stream) {
    const float* rays_o = (const float*)d_in[0];
    const float* rays_d = (const float*)d_in[1];
    const float* G1 = (const float*)d_in[2];
    const float* Fg = (const float*)d_in[3];
    const float* s_w0 = (const float*)d_in[4];
    const float* s_w1 = (const float*)d_in[5];
    const float* s_w2 = (const float*)d_in[6];
    const float* c_w0 = (const float*)d_in[7];
    const float* c_w1 = (const float*)d_in[8];
    const float* c_w2 = (const float*)d_in[9];
    float* out = (float*)d_out;

    const int B = in_sizes[0] / 3;  // 8192 rays
    const int npts = B * 128;

    const size_t FV_OFF = 65536;
    const size_t need = FV_OFF + (size_t)npts * 32;
    if (ws_size < need) return;

    uint4* fv = (uint4*)((char*)d_ws + FV_OFF);

    prep_weights_kernel<<<dim3(19), dim3(64), 0, stream>>>(s_w0, s_w1, s_w2, c_w0, c_w1, c_w2,
                                                           (uint4*)d_ws);
    sample_kernel<<<dim3(npts / 256), dim3(256), 0, stream>>>(rays_o, rays_d, G1, Fg, fv);
    mlp_fp8_kernel<<<dim3(B / 2), dim3(512), 0, stream>>>(rays_o, rays_d, (const uint4*)d_ws,
                                                          fv, out);
}